// Round 8
// baseline (272.248 us; speedup 1.0000x reference)
//
#include <hip/hip_runtime.h>

// LFMA adapter: out = x@W_base^T + b + x @ (alpha * Re(ifft2(scatter(c, mask_idx))))
// Factored: never materialize Delta_W.
//   X[t,k1] = sum_m x[t,m] e^{+2pi i m k1/4096}   (dft_rows_x; Hermitian: store k<=2048, bf16)
//   Y[t,k2] = sum_{nz (k1,k2,c)} c * X[t,k1]      (bucketed sparse spmm)
//   out2[t,n] = SCALE * Re( sum_k2 Y[t,k2] e^{+2pi i n k2/4096} )   (dft_rows_y, WRITES out)
// R8: spmm_col = LDS-staged double-buffered gather: 8 independent dwordx4 loads per
// thread per chunk (structural MLP; R7's compiler-scheduled version kept VGPR=32 and
// serialized), XOR-swizzled LDS slots (write side was a 16-way bank conflict).
// Bucketing: deterministic two-pass (LDS histograms + column scan), no global atomics.
// Base GEMM: kc=8 K-split, dbuf LDS, issue-early/write-late pipeline; reduce_bias sums.

#define TWO_PI 6.28318530717958647692f
constexpr int NROW = 128;
constexpr float SCALE_A = 16.0f / 16777216.0f;
constexpr int NCHUNK = 256;
constexpr int KC = 8;

typedef unsigned short ushort_t;
using short8 = __attribute__((ext_vector_type(8))) short;
using f32x4  = __attribute__((ext_vector_type(4))) float;

__device__ __forceinline__ ushort_t f2bf(float f) {
  unsigned u = __float_as_uint(f);
  u = (u + 0x7FFFu + ((u >> 16) & 1u)) >> 16;   // RNE
  return (ushort_t)u;
}

// ---------------- Kernel A: XTb[k][t] packed bf16 complex, k in [0,2048] (Hermitian).
// grid (128, 2): block qi handles k1 (mod-64 residue) in [qi*32, qi*32+32).
__global__ __launch_bounds__(1024) void dft_rows_x(const float* __restrict__ x,
                                                   unsigned* __restrict__ XTb) {
  __shared__ float xs[4096];
  __shared__ float br[2048], bi[2048];
  __shared__ float2 w64[64];
  const int t = blockIdx.x, qi = blockIdx.y, tid = threadIdx.x;
  const float* xrow = x + (size_t)t * 4096;
#pragma unroll
  for (int l = 0; l < 4; ++l) xs[tid + 1024 * l] = xrow[tid + 1024 * l];
  if (tid < 64) {
    float s, c; __sincosf(TWO_PI * (float)tid * (1.0f / 64.0f), &s, &c);
    w64[tid] = make_float2(c, s);          // W64^j = e^{+2pi i j/64}
  }
  __syncthreads();
  // phase 1: B[m1][k1] for k1 in this block's residue range only
#pragma unroll
  for (int l = 0; l < 2; ++l) {
    int o = tid + 1024 * l, m1 = o >> 5, k1l = o & 31, k1 = qi * 32 + k1l;
    float ar = 0.f, ai = 0.f;
    for (int m2 = 0; m2 < 64; ++m2) {
      float xv = xs[m1 + (m2 << 6)];
      float2 w = w64[(m2 * k1) & 63];
      ar = fmaf(xv, w.x, ar); ai = fmaf(xv, w.y, ai);
    }
    float s, c; __sincosf((float)(m1 * k1) * (TWO_PI / 4096.0f), &s, &c);
    br[(m1 << 5) + k1l] = ar * c - ai * s;
    bi[(m1 << 5) + k1l] = ar * s + ai * c;
  }
  __syncthreads();
  // phase 2: k = k1 + 64*k2, k2 in [0,32) -> covers all k<2048 with this residue
  {
    const int k1l = tid & 31, k2 = tid >> 5;
    const int k = qi * 32 + k1l + (k2 << 6);
    float xr = 0.f, xi = 0.f;
    for (int m1 = 0; m1 < 64; ++m1) {
      float brv = br[(m1 << 5) + k1l], biv = bi[(m1 << 5) + k1l];
      float2 w = w64[(m1 * k2) & 63];
      xr += brv * w.x - biv * w.y;
      xi += brv * w.y + biv * w.x;
    }
    XTb[(size_t)k * NROW + t] = (unsigned)f2bf(xr) | ((unsigned)f2bf(xi) << 16);
    if (qi == 0 && tid == 0) {             // k = 2048: w64^(32*m1) = (-1)^m1
      float xr2 = 0.f, xi2 = 0.f;
      for (int m1 = 0; m1 < 64; ++m1) {
        float sgn = (m1 & 1) ? -1.f : 1.f;
        xr2 = fmaf(sgn, br[m1 << 5], xr2);
        xi2 = fmaf(sgn, bi[m1 << 5], xi2);
      }
      XTb[(size_t)2048 * NROW + t] = (unsigned)f2bf(xr2) | ((unsigned)f2bf(xi2) << 16);
    }
  }
}

// ---------------- S1: per-chunk LDS histogram of k2
__global__ __launch_bounds__(1024) void count_chunks(const int* __restrict__ idx, int K,
                                                     int chunk, int* __restrict__ cnt) {
  __shared__ int h[4096];
  const int c = blockIdx.x, tid = threadIdx.x;
#pragma unroll
  for (int l = 0; l < 4; ++l) h[tid + 1024 * l] = 0;
  __syncthreads();
  const int j0 = c * chunk, j1 = min(j0 + chunk, K);
  for (int j = j0 + tid; j < j1; j += 1024) atomicAdd(&h[idx[j] & 4095], 1);
  __syncthreads();
#pragma unroll
  for (int l = 0; l < 4; ++l) cnt[(size_t)c * 4096 + tid + 1024 * l] = h[tid + 1024 * l];
}

// ---------------- S2: per-column exclusive scan over chunks (in place) + totals
__global__ __launch_bounds__(256) void colscan(int* __restrict__ cnt, int* __restrict__ tot) {
  const int k2 = blockIdx.x * 256 + threadIdx.x;
  int run = 0;
  for (int c8 = 0; c8 < NCHUNK; c8 += 8) {
    int v[8];
#pragma unroll
    for (int i = 0; i < 8; ++i) v[i] = cnt[(size_t)(c8 + i) * 4096 + k2];
#pragma unroll
    for (int i = 0; i < 8; ++i) {
      cnt[(size_t)(c8 + i) * 4096 + k2] = run;
      run += v[i];
    }
  }
  tot[k2] = run;
}

// ---------------- B2: exclusive scan over 4096 totals (single block)
__global__ __launch_bounds__(1024) void scan4096(const int* __restrict__ count,
                                                 int* __restrict__ off) {
  __shared__ int s[4096];
  int tid = threadIdx.x;
#pragma unroll
  for (int l = 0; l < 4; ++l) s[tid + 1024 * l] = count[tid + 1024 * l];
  __syncthreads();
  for (int d = 1; d < 4096; d <<= 1) {
    int v[4];
#pragma unroll
    for (int l = 0; l < 4; ++l) {
      int i = tid + 1024 * l;
      v[l] = s[i] + ((i >= d) ? s[i - d] : 0);
    }
    __syncthreads();
#pragma unroll
    for (int l = 0; l < 4; ++l) s[tid + 1024 * l] = v[l];
    __syncthreads();
  }
#pragma unroll
  for (int l = 0; l < 4; ++l) {
    int i = tid + 1024 * l;
    off[i] = s[i] - count[i];
  }
}

// ---------------- S3: scatter with LDS-rank (no returning global atomics)
__global__ __launch_bounds__(1024) void scatter2(const int* __restrict__ idx,
                                                 const float* __restrict__ cre,
                                                 const float* __restrict__ cim, int K,
                                                 int chunk, const int* __restrict__ base,
                                                 const int* __restrict__ off,
                                                 uint2* __restrict__ bucket) {
  __shared__ int lbase[4096];
  __shared__ int lcur[4096];
  const int c = blockIdx.x, tid = threadIdx.x;
#pragma unroll
  for (int l = 0; l < 4; ++l) {
    int k2 = tid + 1024 * l;
    lbase[k2] = base[(size_t)c * 4096 + k2] + off[k2];
    lcur[k2] = 0;
  }
  __syncthreads();
  const int j0 = c * chunk, j1 = min(j0 + chunk, K);
  for (int j = j0 + tid; j < j1; j += 1024) {
    int p = idx[j];
    int k2 = p & 4095;
    int r = atomicAdd(&lcur[k2], 1);          // LDS atomic: fast
    unsigned cr = f2bf(cre[j]), ci = f2bf(cim[j]);
    bucket[lbase[k2] + r] = make_uint2((unsigned)(p >> 12) | (cr << 16), ci << 16);
  }
}

// ---------------- B4: Y[t][k2] = sum c * X[t,k1]. One block per column.
// LDS-staged double-buffered gather: stage 64 entries' X-rows (512 B each) into LDS
// with 8 independent dwordx4 loads/thread, then 4 waves consume 16 entries each.
__global__ __launch_bounds__(256, 2) void spmm_col(const uint2* __restrict__ bucket,
                                                   const int* __restrict__ off,
                                                   const int* __restrict__ count,
                                                   const unsigned* __restrict__ XTb,
                                                   float2* __restrict__ Y) {
  __shared__ unsigned buf[2][64 * 128];   // [chunk-entry][128 uints], slot-swizzled; 64 KB
  __shared__ uint2 carr[2][64];
  __shared__ float4 red[4][64];
  const int tid = threadIdx.x;
  const int lane = tid & 63;
  const int wid = tid >> 6;
  const int k2 = blockIdx.x;
  const int s = off[k2], n = count[k2];
  const int nch = (n + 63) >> 6;

  const int se = tid >> 2;                // staged entry 0..63
  const int sg = tid & 3;                 // 128-B segment 0..3

  float ar0 = 0.f, ai0 = 0.f, ar1 = 0.f, ai1 = 0.f;
  uint4 rx[8];
  uint2 ent;

  // ---- issue: 8 independent 16-B gathers for chunk c (entry se, segment sg)
  auto issue = [&](int c) {
    int j = c * 64 + se;
    ent = (j < n) ? bucket[s + j] : make_uint2(0u, 0u);   // OOB -> c=0 (no-op entry)
    int k1 = (int)(ent.x & 0xfffu);
    int r = (k1 > 2048) ? 4096 - k1 : k1;
    const uint4* src = (const uint4*)(XTb + (size_t)r * NROW) + sg * 8;
#pragma unroll
    for (int u = 0; u < 8; ++u) rx[u] = src[u];
  };
  // ---- commit: regs -> LDS buf[p], slot XOR-swizzled by entry (bank spread)
  auto commit = [&](int p) {
#pragma unroll
    for (int u = 0; u < 8; ++u) {
      int slot = sg * 8 + u;
      int pslot = slot ^ (se & 7);
      *(uint4*)(&buf[p][se * 128 + pslot * 4]) = rx[u];
    }
    if (sg == 0) carr[p][se] = ent;
  };

  issue(0); commit(0);
  __syncthreads();
  int p = 0;
  for (int c = 0; c < nch; ++c) {
    if (c + 1 < nch) issue(c + 1);        // loads in flight under compute
    const int ebase = wid * 16;
#pragma unroll
    for (int i = 0; i < 16; ++i) {
      int e = ebase + i;
      uint2 cw = carr[p][e];              // broadcast read
      unsigned w0 = cw.x, w1 = cw.y;
      int k1 = (int)(w0 & 0xfffu);
      unsigned negm = (k1 > 2048) ? 0x80000000u : 0u;
      unsigned crb = w0 & 0xffff0000u;
      float cr  = __int_as_float((int)crb);
      float ci  = __int_as_float((int)w1);
      float crs = __int_as_float((int)(crb ^ negm));
      float cis = __int_as_float((int)(w1 ^ negm));
      int pslot = (lane >> 1) ^ (i & 7);  // ebase%8==0 -> e&7 == i&7
      uint2 xv = *(const uint2*)(&buf[p][e * 128 + pslot * 4 + (lane & 1) * 2]);
      float xr0 = __int_as_float((int)(xv.x << 16));
      float xi0 = __int_as_float((int)(xv.x & 0xffff0000u));
      float xr1 = __int_as_float((int)(xv.y << 16));
      float xi1 = __int_as_float((int)(xv.y & 0xffff0000u));
      ar0 = fmaf(cr, xr0, ar0);  ar0 = fmaf(-cis, xi0, ar0);
      ai0 = fmaf(crs, xi0, ai0); ai0 = fmaf(ci, xr0, ai0);
      ar1 = fmaf(cr, xr1, ar1);  ar1 = fmaf(-cis, xi1, ar1);
      ai1 = fmaf(crs, xi1, ai1); ai1 = fmaf(ci, xr1, ai1);
    }
    if (c + 1 < nch) commit(p ^ 1);       // other buffer: no hazard with readers of p
    __syncthreads();
    p ^= 1;
  }
  if (wid) red[wid][lane] = make_float4(ar0, ai0, ar1, ai1);
  __syncthreads();
  if (wid == 0) {
#pragma unroll
    for (int w = 1; w < 4; ++w) {
      float4 o = red[w][lane];
      ar0 += o.x; ai0 += o.y; ar1 += o.z; ai1 += o.w;
    }
    Y[(size_t)(2 * lane) * 4096 + k2]     = make_float2(ar0, ai0);
    Y[(size_t)(2 * lane + 1) * 4096 + k2] = make_float2(ar1, ai1);
  }
}

// ---------------- Kernel C: out[t][n] = SCALE * Re(DFT-4096 of Y row). grid (128,2).
// Block qi handles n1 (mod-64 residue) in [qi*32, qi*32+32). WRITES out.
__global__ __launch_bounds__(1024) void dft_rows_y(const float2* __restrict__ Y,
                                                   float* __restrict__ out) {
  __shared__ float ysr[4096], ysi[4096];
  __shared__ float br[2048], bi[2048];
  __shared__ float2 w64[64];
  const int t = blockIdx.x, qi = blockIdx.y, tid = threadIdx.x;
  const float2* yrow = Y + (size_t)t * 4096;
#pragma unroll
  for (int l = 0; l < 4; ++l) {
    float2 v = yrow[tid + 1024 * l];
    ysr[tid + 1024 * l] = v.x; ysi[tid + 1024 * l] = v.y;
  }
  if (tid < 64) {
    float s, c; __sincosf(TWO_PI * (float)tid * (1.0f / 64.0f), &s, &c);
    w64[tid] = make_float2(c, s);
  }
  __syncthreads();
  // phase 1: B[a][n1] for n1 in this block's residue range
#pragma unroll
  for (int l = 0; l < 2; ++l) {
    int o = tid + 1024 * l, a = o >> 5, n1l = o & 31, n1 = qi * 32 + n1l;
    float ar = 0.f, ai = 0.f;
    for (int b = 0; b < 64; ++b) {
      float yr = ysr[a + (b << 6)], yi = ysi[a + (b << 6)];
      float2 w = w64[(n1 * b) & 63];
      ar += yr * w.x - yi * w.y;
      ai += yr * w.y + yi * w.x;
    }
    float s, c; __sincosf((float)(n1 * a) * (TWO_PI / 4096.0f), &s, &c);
    br[(a << 5) + n1l] = ar * c - ai * s;
    bi[(a << 5) + n1l] = ar * s + ai * c;
  }
  __syncthreads();
  // phase 2: n = n1 + 64*n2, n2 in [0,64)
  float* orow = out + (size_t)t * 4096;
  const int n1l = tid & 31;
  const int n1 = qi * 32 + n1l;
#pragma unroll
  for (int l = 0; l < 2; ++l) {
    int n2 = (tid >> 5) + 32 * l;
    float acc = 0.f;
    for (int a = 0; a < 64; ++a) {
      float brv = br[(a << 5) + n1l], biv = bi[(a << 5) + n1l];
      float2 w = w64[(n2 * a) & 63];
      acc += brv * w.x - biv * w.y;
    }
    orow[n1 + (n2 << 6)] = acc * SCALE_A;
  }
}

// ---------------- x -> bf16 pre-convert
__global__ __launch_bounds__(256) void xcvt(const float* __restrict__ x,
                                            ushort_t* __restrict__ xbf) {
  size_t e = ((size_t)blockIdx.x * 256 + threadIdx.x) * 4;
  float4 v = *(const float4*)(x + e);
  unsigned lo = (unsigned)f2bf(v.x) | ((unsigned)f2bf(v.y) << 16);
  unsigned hi = (unsigned)f2bf(v.z) | ((unsigned)f2bf(v.w) << 16);
  *(uint2*)(xbf + e) = make_uint2(lo, hi);
}

// ---------------- base GEMM partials: part[kc][t][f], tile 128(t) x 64(f) x 64(k)
__global__ __launch_bounds__(256) void gemm_mfma_partial(const ushort_t* __restrict__ xbf,
                                                         const float* __restrict__ W,
                                                         float* __restrict__ part) {
  __shared__ ushort_t xs[2][128 * 64];
  __shared__ ushort_t wsl[2][64 * 64];
  const int f0 = blockIdx.x * 64;
  const int kc = blockIdx.y;
  const int tid = threadIdx.x;
  const int w = tid >> 6, lane = tid & 63;

  f32x4 acc[2][4];
#pragma unroll
  for (int i = 0; i < 2; ++i)
#pragma unroll
    for (int j = 0; j < 4; ++j) acc[i][j] = (f32x4){0.f, 0.f, 0.f, 0.f};

  uint4 rx[4];
  float4 rwa[2], rwb[2];
  const int kbeg = kc * 512;

#pragma unroll
  for (int l = 0; l < 4; ++l) {
    int s = tid + 256 * l, r = s >> 3, ks = s & 7;
    rx[l] = *(const uint4*)(xbf + (size_t)r * 4096 + kbeg + ks * 8);
  }
#pragma unroll
  for (int l = 0; l < 2; ++l) {
    int s = tid + 256 * l, r = s >> 3, ks = s & 7;
    const float* wp = W + (size_t)(f0 + r) * 4096 + kbeg + ks * 8;
    rwa[l] = *(const float4*)(wp);
    rwb[l] = *(const float4*)(wp + 4);
  }

  int cur = 0;
  for (int st = 0; st < 8; ++st) {
#pragma unroll
    for (int l = 0; l < 4; ++l) {
      int s = tid + 256 * l, r = s >> 3, ks = s & 7;
      *(uint4*)(&xs[cur][r * 64 + ((ks ^ (r & 7)) << 3)]) = rx[l];
    }
#pragma unroll
    for (int l = 0; l < 2; ++l) {
      int s = tid + 256 * l, r = s >> 3, ks = s & 7;
      uint4 pk;
      pk.x = (unsigned)f2bf(rwa[l].x) | ((unsigned)f2bf(rwa[l].y) << 16);
      pk.y = (unsigned)f2bf(rwa[l].z) | ((unsigned)f2bf(rwa[l].w) << 16);
      pk.z = (unsigned)f2bf(rwb[l].x) | ((unsigned)f2bf(rwb[l].y) << 16);
      pk.w = (unsigned)f2bf(rwb[l].z) | ((unsigned)f2bf(rwb[l].w) << 16);
      *(uint4*)(&wsl[cur][r * 64 + ((ks ^ (r & 7)) << 3)]) = pk;
    }
    __syncthreads();
    if (st < 7) {
      const int k0 = kbeg + (st + 1) * 64;
#pragma unroll
      for (int l = 0; l < 4; ++l) {
        int s = tid + 256 * l, r = s >> 3, ks = s & 7;
        rx[l] = *(const uint4*)(xbf + (size_t)r * 4096 + k0 + ks * 8);
      }
#pragma unroll
      for (int l = 0; l < 2; ++l) {
        int s = tid + 256 * l, r = s >> 3, ks = s & 7;
        const float* wp = W + (size_t)(f0 + r) * 4096 + k0 + ks * 8;
        rwa[l] = *(const float4*)(wp);
        rwb[l] = *(const float4*)(wp + 4);
      }
    }
#pragma unroll
    for (int kk = 0; kk < 2; ++kk) {
      int ksA = kk * 4 + (lane >> 4);
      short8 af[2], bfr[4];
#pragma unroll
      for (int mf = 0; mf < 2; ++mf) {
        int ra = w * 32 + mf * 16 + (lane & 15);
        af[mf] = *(const short8*)(&xs[cur][ra * 64 + ((ksA ^ (ra & 7)) << 3)]);
      }
#pragma unroll
      for (int nf = 0; nf < 4; ++nf) {
        int rb = nf * 16 + (lane & 15);
        bfr[nf] = *(const short8*)(&wsl[cur][rb * 64 + ((ksA ^ (rb & 7)) << 3)]);
      }
#pragma unroll
      for (int mf = 0; mf < 2; ++mf)
#pragma unroll
        for (int nf = 0; nf < 4; ++nf)
          acc[mf][nf] = __builtin_amdgcn_mfma_f32_16x16x32_bf16(af[mf], bfr[nf], acc[mf][nf], 0, 0, 0);
    }
    cur ^= 1;
  }
  float* pb = part + ((size_t)kc << 19);
#pragma unroll
  for (int mf = 0; mf < 2; ++mf)
#pragma unroll
    for (int nf = 0; nf < 4; ++nf)
#pragma unroll
      for (int reg = 0; reg < 4; ++reg) {
        int row = w * 32 + mf * 16 + (lane >> 4) * 4 + reg;
        int col = f0 + nf * 16 + (lane & 15);
        pb[(size_t)row * 4096 + col] = acc[mf][nf][reg];
      }
}

// ---------------- out += bias + sum of KC partials (out already holds dft_y result)
__global__ __launch_bounds__(256) void reduce_bias(const float* __restrict__ part,
                                                   const float* __restrict__ b,
                                                   float* __restrict__ out) {
  size_t e = ((size_t)blockIdx.x * 256 + threadIdx.x) * 4;
  int f = (int)(e & 4095);
  float4 o  = *(const float4*)(out + e);
  float4 bb = *(const float4*)(b + f);
  float sx = o.x + bb.x, sy = o.y + bb.y, sz = o.z + bb.z, sw = o.w + bb.w;
#pragma unroll
  for (int i = 0; i < KC; ++i) {
    float4 v = *(const float4*)(part + e + ((size_t)i << 19));
    sx += v.x; sy += v.y; sz += v.z; sw += v.w;
  }
  *(float4*)(out + e) = make_float4(sx, sy, sz, sw);
}

extern "C" void kernel_launch(void* const* d_in, const int* in_sizes, int n_in,
                              void* d_out, int out_size, void* d_ws, size_t ws_size,
                              hipStream_t stream) {
  const float* x   = (const float*)d_in[0];
  const float* W   = (const float*)d_in[1];
  const float* b   = (const float*)d_in[2];
  const float* cre = (const float*)d_in[3];
  const float* cim = (const float*)d_in[4];
  const int* midx  = (const int*)d_in[5];
  const int K = in_sizes[3];
  float* out = (float*)d_out;
  const int chunk = (K + NCHUNK - 1) / NCHUNK;

  char* ws = (char*)d_ws;
  unsigned* XTb  = (unsigned*)(ws);                        // ~1.05 MB
  float2* Y      = (float2*)(ws + (size_t)(2 << 20));      // 4 MB
  uint2* bucket  = (uint2*)(ws + (size_t)(6 << 20));       // K*8 ~= 6.7 MB (ends <13M)
  int* cnt       = (int*)(ws + (size_t)(13 << 20));        // 4 MB (ends 17M)
  char* meta     = ws + (size_t)(17 << 20);                // tot/off 32 KB
  int* tot = (int*)(meta);
  int* off = (int*)(meta + 16384);
  ushort_t* xbf  = (ushort_t*)(ws + (size_t)(18 << 20));   // 1 MB (ends 19M)
  float* part    = (float*)(ws + (size_t)(2 << 20));       // KC*2MB = 16 MB (ends 18M);
  // part ALIASES Y/bucket/cnt/meta — all fully consumed before gemm runs.

  xcvt<<<512, 256, 0, stream>>>(x, xbf);
  dft_rows_x<<<dim3(NROW, 2), 1024, 0, stream>>>(x, XTb);
  count_chunks<<<NCHUNK, 1024, 0, stream>>>(midx, K, chunk, cnt);
  colscan<<<16, 256, 0, stream>>>(cnt, tot);
  scan4096<<<1, 1024, 0, stream>>>(tot, off);
  scatter2<<<NCHUNK, 1024, 0, stream>>>(midx, cre, cim, K, chunk, cnt, off, bucket);
  spmm_col<<<4096, 256, 0, stream>>>(bucket, off, tot, XTb, Y);
  dft_rows_y<<<dim3(NROW, 2), 1024, 0, stream>>>(Y, out);      // writes out2
  gemm_mfma_partial<<<dim3(64, KC), 256, 0, stream>>>(xbf, W, part);
  reduce_bias<<<512, 256, 0, stream>>>(part, b, out);          // out += b + sum(part)
}

// Round 9
// 141.313 us; speedup vs baseline: 1.9266x; 1.9266x over previous
//
#include <hip/hip_runtime.h>

// LFMA adapter: out = x@W_base^T + b + x @ (alpha * Re(ifft2(scatter(c, mask_idx))))
// Factored: never materialize Delta_W.
//   X[t,k1] = sum_m x[t,m] e^{+2pi i m k1/4096}   (dft_rows_x; Hermitian: store k<=2048, bf16)
//   Y[t,k2] = sum_{nz (k1,k2,c)} c * X[t,k1]      (bucketed sparse, readlane-broadcast spmm)
//   out2[t,n] = SCALE * Re( sum_k2 Y[t,k2] e^{+2pi i n k2/4096} )   (dft_rows_y, WRITES out)
// R9: spmm = R7 structure (R8's LDS-staged version spilled rx[] to scratch: 409 MB
// writes/dispatch, 181us - reverted) + __launch_bounds__(256,4): R7's group-8 pipeline
// was re-serialized by the compiler at VGPR=32 (max-occupancy target); min-4-waves/EU
// raises the budget to ~128 VGPR so 8 gathers can actually be in flight.
// Bucketing: deterministic two-pass (LDS histograms + column scan), no global atomics.
// Base GEMM: kc=8 K-split, dbuf LDS, issue-early/write-late pipeline; reduce_bias sums.

#define TWO_PI 6.28318530717958647692f
constexpr int NROW = 128;
constexpr float SCALE_A = 16.0f / 16777216.0f;
constexpr int NCHUNK = 256;
constexpr int KC = 8;

typedef unsigned short ushort_t;
using short8 = __attribute__((ext_vector_type(8))) short;
using f32x4  = __attribute__((ext_vector_type(4))) float;

__device__ __forceinline__ ushort_t f2bf(float f) {
  unsigned u = __float_as_uint(f);
  u = (u + 0x7FFFu + ((u >> 16) & 1u)) >> 16;   // RNE
  return (ushort_t)u;
}

// ---------------- Kernel A: XTb[k][t] packed bf16 complex, k in [0,2048] (Hermitian).
// grid (128, 2): block qi handles k1 (mod-64 residue) in [qi*32, qi*32+32).
__global__ __launch_bounds__(1024) void dft_rows_x(const float* __restrict__ x,
                                                   unsigned* __restrict__ XTb) {
  __shared__ float xs[4096];
  __shared__ float br[2048], bi[2048];
  __shared__ float2 w64[64];
  const int t = blockIdx.x, qi = blockIdx.y, tid = threadIdx.x;
  const float* xrow = x + (size_t)t * 4096;
#pragma unroll
  for (int l = 0; l < 4; ++l) xs[tid + 1024 * l] = xrow[tid + 1024 * l];
  if (tid < 64) {
    float s, c; __sincosf(TWO_PI * (float)tid * (1.0f / 64.0f), &s, &c);
    w64[tid] = make_float2(c, s);          // W64^j = e^{+2pi i j/64}
  }
  __syncthreads();
  // phase 1: B[m1][k1] for k1 in this block's residue range only
#pragma unroll
  for (int l = 0; l < 2; ++l) {
    int o = tid + 1024 * l, m1 = o >> 5, k1l = o & 31, k1 = qi * 32 + k1l;
    float ar = 0.f, ai = 0.f;
    for (int m2 = 0; m2 < 64; ++m2) {
      float xv = xs[m1 + (m2 << 6)];
      float2 w = w64[(m2 * k1) & 63];
      ar = fmaf(xv, w.x, ar); ai = fmaf(xv, w.y, ai);
    }
    float s, c; __sincosf((float)(m1 * k1) * (TWO_PI / 4096.0f), &s, &c);
    br[(m1 << 5) + k1l] = ar * c - ai * s;
    bi[(m1 << 5) + k1l] = ar * s + ai * c;
  }
  __syncthreads();
  // phase 2: k = k1 + 64*k2, k2 in [0,32) -> covers all k<2048 with this residue
  {
    const int k1l = tid & 31, k2 = tid >> 5;
    const int k = qi * 32 + k1l + (k2 << 6);
    float xr = 0.f, xi = 0.f;
    for (int m1 = 0; m1 < 64; ++m1) {
      float brv = br[(m1 << 5) + k1l], biv = bi[(m1 << 5) + k1l];
      float2 w = w64[(m1 * k2) & 63];
      xr += brv * w.x - biv * w.y;
      xi += brv * w.y + biv * w.x;
    }
    XTb[(size_t)k * NROW + t] = (unsigned)f2bf(xr) | ((unsigned)f2bf(xi) << 16);
    if (qi == 0 && tid == 0) {             // k = 2048: w64^(32*m1) = (-1)^m1
      float xr2 = 0.f, xi2 = 0.f;
      for (int m1 = 0; m1 < 64; ++m1) {
        float sgn = (m1 & 1) ? -1.f : 1.f;
        xr2 = fmaf(sgn, br[m1 << 5], xr2);
        xi2 = fmaf(sgn, bi[m1 << 5], xi2);
      }
      XTb[(size_t)2048 * NROW + t] = (unsigned)f2bf(xr2) | ((unsigned)f2bf(xi2) << 16);
    }
  }
}

// ---------------- S1: per-chunk LDS histogram of k2
__global__ __launch_bounds__(1024) void count_chunks(const int* __restrict__ idx, int K,
                                                     int chunk, int* __restrict__ cnt) {
  __shared__ int h[4096];
  const int c = blockIdx.x, tid = threadIdx.x;
#pragma unroll
  for (int l = 0; l < 4; ++l) h[tid + 1024 * l] = 0;
  __syncthreads();
  const int j0 = c * chunk, j1 = min(j0 + chunk, K);
  for (int j = j0 + tid; j < j1; j += 1024) atomicAdd(&h[idx[j] & 4095], 1);
  __syncthreads();
#pragma unroll
  for (int l = 0; l < 4; ++l) cnt[(size_t)c * 4096 + tid + 1024 * l] = h[tid + 1024 * l];
}

// ---------------- S2: per-column exclusive scan over chunks (in place) + totals
__global__ __launch_bounds__(256) void colscan(int* __restrict__ cnt, int* __restrict__ tot) {
  const int k2 = blockIdx.x * 256 + threadIdx.x;
  int run = 0;
  for (int c8 = 0; c8 < NCHUNK; c8 += 8) {
    int v[8];
#pragma unroll
    for (int i = 0; i < 8; ++i) v[i] = cnt[(size_t)(c8 + i) * 4096 + k2];
#pragma unroll
    for (int i = 0; i < 8; ++i) {
      cnt[(size_t)(c8 + i) * 4096 + k2] = run;
      run += v[i];
    }
  }
  tot[k2] = run;
}

// ---------------- B2: exclusive scan over 4096 totals (single block)
__global__ __launch_bounds__(1024) void scan4096(const int* __restrict__ count,
                                                 int* __restrict__ off) {
  __shared__ int s[4096];
  int tid = threadIdx.x;
#pragma unroll
  for (int l = 0; l < 4; ++l) s[tid + 1024 * l] = count[tid + 1024 * l];
  __syncthreads();
  for (int d = 1; d < 4096; d <<= 1) {
    int v[4];
#pragma unroll
    for (int l = 0; l < 4; ++l) {
      int i = tid + 1024 * l;
      v[l] = s[i] + ((i >= d) ? s[i - d] : 0);
    }
    __syncthreads();
#pragma unroll
    for (int l = 0; l < 4; ++l) s[tid + 1024 * l] = v[l];
    __syncthreads();
  }
#pragma unroll
  for (int l = 0; l < 4; ++l) {
    int i = tid + 1024 * l;
    off[i] = s[i] - count[i];
  }
}

// ---------------- S3: scatter with LDS-rank (no returning global atomics)
__global__ __launch_bounds__(1024) void scatter2(const int* __restrict__ idx,
                                                 const float* __restrict__ cre,
                                                 const float* __restrict__ cim, int K,
                                                 int chunk, const int* __restrict__ base,
                                                 const int* __restrict__ off,
                                                 uint2* __restrict__ bucket) {
  __shared__ int lbase[4096];
  __shared__ int lcur[4096];
  const int c = blockIdx.x, tid = threadIdx.x;
#pragma unroll
  for (int l = 0; l < 4; ++l) {
    int k2 = tid + 1024 * l;
    lbase[k2] = base[(size_t)c * 4096 + k2] + off[k2];
    lcur[k2] = 0;
  }
  __syncthreads();
  const int j0 = c * chunk, j1 = min(j0 + chunk, K);
  for (int j = j0 + tid; j < j1; j += 1024) {
    int p = idx[j];
    int k2 = p & 4095;
    int r = atomicAdd(&lcur[k2], 1);          // LDS atomic: fast
    unsigned cr = f2bf(cre[j]), ci = f2bf(cim[j]);
    bucket[lbase[k2] + r] = make_uint2((unsigned)(p >> 12) | (cr << 16), ci << 16);
  }
}

// ---------------- B4: Y[t][k2] = sum c * X[t,k1]. 2 waves per column, 2 cols/block.
// Group-8 software pipeline; __launch_bounds__(256,4) gives the register allocator
// budget (~128 VGPR) to keep the 8 gathers in flight (at plain (256) it kept VGPR=32
// and serialized them - R7 null result).
__global__ __launch_bounds__(256, 4) void spmm_col(const uint2* __restrict__ bucket,
                                                   const int* __restrict__ off,
                                                   const int* __restrict__ count,
                                                   const unsigned* __restrict__ XTb,
                                                   float2* __restrict__ Y) {
  __shared__ float4 red[2][64];
  const int lane = threadIdx.x & 63;
  const int wid = threadIdx.x >> 6;
  const int colsel = wid >> 1, half = wid & 1;
  const int k2 = blockIdx.x * 2 + colsel;
  const int s = off[k2], n = count[k2];
  float ar0 = 0.f, ai0 = 0.f, ar1 = 0.f, ai1 = 0.f;
  for (int c = half * 64; c < n; c += 128) {
    int idx = c + lane;
    uint2 ec = (idx < n) ? bucket[s + idx] : make_uint2(0u, 0u);
#pragma unroll
    for (int g = 0; g < 64; g += 8) {
      uint2 xv[8];
      int crb[8], cib[8], negm[8];
#pragma unroll
      for (int u = 0; u < 8; ++u) {
        int w0 = __builtin_amdgcn_readlane((int)ec.x, g + u);
        int w1 = __builtin_amdgcn_readlane((int)ec.y, g + u);
        int k1 = w0 & 0xfff;
        negm[u] = (k1 > 2048) ? (int)0x80000000 : 0;
        int r = (k1 > 2048) ? 4096 - k1 : k1;
        crb[u] = w0 & 0xffff0000;
        cib[u] = w1;
        xv[u] = *(const uint2*)(XTb + (size_t)r * NROW + 2 * lane);
      }
#pragma unroll
      for (int u = 0; u < 8; ++u) {
        float cr  = __int_as_float(crb[u]);
        float ci  = __int_as_float(cib[u]);
        float crs = __int_as_float(crb[u] ^ negm[u]);
        float cis = __int_as_float(cib[u] ^ negm[u]);
        float xr0 = __int_as_float(xv[u].x << 16);
        float xi0 = __int_as_float(xv[u].x & 0xffff0000u);
        float xr1 = __int_as_float(xv[u].y << 16);
        float xi1 = __int_as_float(xv[u].y & 0xffff0000u);
        ar0 = fmaf(cr, xr0, ar0);  ar0 = fmaf(-cis, xi0, ar0);
        ai0 = fmaf(crs, xi0, ai0); ai0 = fmaf(ci, xr0, ai0);
        ar1 = fmaf(cr, xr1, ar1);  ar1 = fmaf(-cis, xi1, ar1);
        ai1 = fmaf(crs, xi1, ai1); ai1 = fmaf(ci, xr1, ai1);
      }
    }
  }
  if (half == 1) red[colsel][lane] = make_float4(ar0, ai0, ar1, ai1);
  __syncthreads();
  if (half == 0) {
    float4 o = red[colsel][lane];
    ar0 += o.x; ai0 += o.y; ar1 += o.z; ai1 += o.w;
    Y[(size_t)(2 * lane) * 4096 + k2]     = make_float2(ar0, ai0);
    Y[(size_t)(2 * lane + 1) * 4096 + k2] = make_float2(ar1, ai1);
  }
}

// ---------------- Kernel C: out[t][n] = SCALE * Re(DFT-4096 of Y row). grid (128,2).
// Block qi handles n1 (mod-64 residue) in [qi*32, qi*32+32). WRITES out.
__global__ __launch_bounds__(1024) void dft_rows_y(const float2* __restrict__ Y,
                                                   float* __restrict__ out) {
  __shared__ float ysr[4096], ysi[4096];
  __shared__ float br[2048], bi[2048];
  __shared__ float2 w64[64];
  const int t = blockIdx.x, qi = blockIdx.y, tid = threadIdx.x;
  const float2* yrow = Y + (size_t)t * 4096;
#pragma unroll
  for (int l = 0; l < 4; ++l) {
    float2 v = yrow[tid + 1024 * l];
    ysr[tid + 1024 * l] = v.x; ysi[tid + 1024 * l] = v.y;
  }
  if (tid < 64) {
    float s, c; __sincosf(TWO_PI * (float)tid * (1.0f / 64.0f), &s, &c);
    w64[tid] = make_float2(c, s);
  }
  __syncthreads();
  // phase 1: B[a][n1] for n1 in this block's residue range
#pragma unroll
  for (int l = 0; l < 2; ++l) {
    int o = tid + 1024 * l, a = o >> 5, n1l = o & 31, n1 = qi * 32 + n1l;
    float ar = 0.f, ai = 0.f;
    for (int b = 0; b < 64; ++b) {
      float yr = ysr[a + (b << 6)], yi = ysi[a + (b << 6)];
      float2 w = w64[(n1 * b) & 63];
      ar += yr * w.x - yi * w.y;
      ai += yr * w.y + yi * w.x;
    }
    float s, c; __sincosf((float)(n1 * a) * (TWO_PI / 4096.0f), &s, &c);
    br[(a << 5) + n1l] = ar * c - ai * s;
    bi[(a << 5) + n1l] = ar * s + ai * c;
  }
  __syncthreads();
  // phase 2: n = n1 + 64*n2, n2 in [0,64)
  float* orow = out + (size_t)t * 4096;
  const int n1l = tid & 31;
  const int n1 = qi * 32 + n1l;
#pragma unroll
  for (int l = 0; l < 2; ++l) {
    int n2 = (tid >> 5) + 32 * l;
    float acc = 0.f;
    for (int a = 0; a < 64; ++a) {
      float brv = br[(a << 5) + n1l], biv = bi[(a << 5) + n1l];
      float2 w = w64[(n2 * a) & 63];
      acc += brv * w.x - biv * w.y;
    }
    orow[n1 + (n2 << 6)] = acc * SCALE_A;
  }
}

// ---------------- x -> bf16 pre-convert
__global__ __launch_bounds__(256) void xcvt(const float* __restrict__ x,
                                            ushort_t* __restrict__ xbf) {
  size_t e = ((size_t)blockIdx.x * 256 + threadIdx.x) * 4;
  float4 v = *(const float4*)(x + e);
  unsigned lo = (unsigned)f2bf(v.x) | ((unsigned)f2bf(v.y) << 16);
  unsigned hi = (unsigned)f2bf(v.z) | ((unsigned)f2bf(v.w) << 16);
  *(uint2*)(xbf + e) = make_uint2(lo, hi);
}

// ---------------- base GEMM partials: part[kc][t][f], tile 128(t) x 64(f) x 64(k)
__global__ __launch_bounds__(256) void gemm_mfma_partial(const ushort_t* __restrict__ xbf,
                                                         const float* __restrict__ W,
                                                         float* __restrict__ part) {
  __shared__ ushort_t xs[2][128 * 64];
  __shared__ ushort_t wsl[2][64 * 64];
  const int f0 = blockIdx.x * 64;
  const int kc = blockIdx.y;
  const int tid = threadIdx.x;
  const int w = tid >> 6, lane = tid & 63;

  f32x4 acc[2][4];
#pragma unroll
  for (int i = 0; i < 2; ++i)
#pragma unroll
    for (int j = 0; j < 4; ++j) acc[i][j] = (f32x4){0.f, 0.f, 0.f, 0.f};

  uint4 rx[4];
  float4 rwa[2], rwb[2];
  const int kbeg = kc * 512;

#pragma unroll
  for (int l = 0; l < 4; ++l) {
    int s = tid + 256 * l, r = s >> 3, ks = s & 7;
    rx[l] = *(const uint4*)(xbf + (size_t)r * 4096 + kbeg + ks * 8);
  }
#pragma unroll
  for (int l = 0; l < 2; ++l) {
    int s = tid + 256 * l, r = s >> 3, ks = s & 7;
    const float* wp = W + (size_t)(f0 + r) * 4096 + kbeg + ks * 8;
    rwa[l] = *(const float4*)(wp);
    rwb[l] = *(const float4*)(wp + 4);
  }

  int cur = 0;
  for (int st = 0; st < 8; ++st) {
#pragma unroll
    for (int l = 0; l < 4; ++l) {
      int s = tid + 256 * l, r = s >> 3, ks = s & 7;
      *(uint4*)(&xs[cur][r * 64 + ((ks ^ (r & 7)) << 3)]) = rx[l];
    }
#pragma unroll
    for (int l = 0; l < 2; ++l) {
      int s = tid + 256 * l, r = s >> 3, ks = s & 7;
      uint4 pk;
      pk.x = (unsigned)f2bf(rwa[l].x) | ((unsigned)f2bf(rwa[l].y) << 16);
      pk.y = (unsigned)f2bf(rwa[l].z) | ((unsigned)f2bf(rwa[l].w) << 16);
      pk.z = (unsigned)f2bf(rwb[l].x) | ((unsigned)f2bf(rwb[l].y) << 16);
      pk.w = (unsigned)f2bf(rwb[l].z) | ((unsigned)f2bf(rwb[l].w) << 16);
      *(uint4*)(&wsl[cur][r * 64 + ((ks ^ (r & 7)) << 3)]) = pk;
    }
    __syncthreads();
    if (st < 7) {
      const int k0 = kbeg + (st + 1) * 64;
#pragma unroll
      for (int l = 0; l < 4; ++l) {
        int s = tid + 256 * l, r = s >> 3, ks = s & 7;
        rx[l] = *(const uint4*)(xbf + (size_t)r * 4096 + k0 + ks * 8);
      }
#pragma unroll
      for (int l = 0; l < 2; ++l) {
        int s = tid + 256 * l, r = s >> 3, ks = s & 7;
        const float* wp = W + (size_t)(f0 + r) * 4096 + k0 + ks * 8;
        rwa[l] = *(const float4*)(wp);
        rwb[l] = *(const float4*)(wp + 4);
      }
    }
#pragma unroll
    for (int kk = 0; kk < 2; ++kk) {
      int ksA = kk * 4 + (lane >> 4);
      short8 af[2], bfr[4];
#pragma unroll
      for (int mf = 0; mf < 2; ++mf) {
        int ra = w * 32 + mf * 16 + (lane & 15);
        af[mf] = *(const short8*)(&xs[cur][ra * 64 + ((ksA ^ (ra & 7)) << 3)]);
      }
#pragma unroll
      for (int nf = 0; nf < 4; ++nf) {
        int rb = nf * 16 + (lane & 15);
        bfr[nf] = *(const short8*)(&wsl[cur][rb * 64 + ((ksA ^ (rb & 7)) << 3)]);
      }
#pragma unroll
      for (int mf = 0; mf < 2; ++mf)
#pragma unroll
        for (int nf = 0; nf < 4; ++nf)
          acc[mf][nf] = __builtin_amdgcn_mfma_f32_16x16x32_bf16(af[mf], bfr[nf], acc[mf][nf], 0, 0, 0);
    }
    cur ^= 1;
  }
  float* pb = part + ((size_t)kc << 19);
#pragma unroll
  for (int mf = 0; mf < 2; ++mf)
#pragma unroll
    for (int nf = 0; nf < 4; ++nf)
#pragma unroll
      for (int reg = 0; reg < 4; ++reg) {
        int row = w * 32 + mf * 16 + (lane >> 4) * 4 + reg;
        int col = f0 + nf * 16 + (lane & 15);
        pb[(size_t)row * 4096 + col] = acc[mf][nf][reg];
      }
}

// ---------------- out += bias + sum of KC partials (out already holds dft_y result)
__global__ __launch_bounds__(256) void reduce_bias(const float* __restrict__ part,
                                                   const float* __restrict__ b,
                                                   float* __restrict__ out) {
  size_t e = ((size_t)blockIdx.x * 256 + threadIdx.x) * 4;
  int f = (int)(e & 4095);
  float4 o  = *(const float4*)(out + e);
  float4 bb = *(const float4*)(b + f);
  float sx = o.x + bb.x, sy = o.y + bb.y, sz = o.z + bb.z, sw = o.w + bb.w;
#pragma unroll
  for (int i = 0; i < KC; ++i) {
    float4 v = *(const float4*)(part + e + ((size_t)i << 19));
    sx += v.x; sy += v.y; sz += v.z; sw += v.w;
  }
  *(float4*)(out + e) = make_float4(sx, sy, sz, sw);
}

extern "C" void kernel_launch(void* const* d_in, const int* in_sizes, int n_in,
                              void* d_out, int out_size, void* d_ws, size_t ws_size,
                              hipStream_t stream) {
  const float* x   = (const float*)d_in[0];
  const float* W   = (const float*)d_in[1];
  const float* b   = (const float*)d_in[2];
  const float* cre = (const float*)d_in[3];
  const float* cim = (const float*)d_in[4];
  const int* midx  = (const int*)d_in[5];
  const int K = in_sizes[3];
  float* out = (float*)d_out;
  const int chunk = (K + NCHUNK - 1) / NCHUNK;

  char* ws = (char*)d_ws;
  unsigned* XTb  = (unsigned*)(ws);                        // ~1.05 MB
  float2* Y      = (float2*)(ws + (size_t)(2 << 20));      // 4 MB
  uint2* bucket  = (uint2*)(ws + (size_t)(6 << 20));       // K*8 ~= 6.7 MB (ends <13M)
  int* cnt       = (int*)(ws + (size_t)(13 << 20));        // 4 MB (ends 17M)
  char* meta     = ws + (size_t)(17 << 20);                // tot/off 32 KB
  int* tot = (int*)(meta);
  int* off = (int*)(meta + 16384);
  ushort_t* xbf  = (ushort_t*)(ws + (size_t)(18 << 20));   // 1 MB (ends 19M)
  float* part    = (float*)(ws + (size_t)(2 << 20));       // KC*2MB = 16 MB (ends 18M);
  // part ALIASES Y/bucket/cnt/meta — all fully consumed before gemm runs.

  xcvt<<<512, 256, 0, stream>>>(x, xbf);
  dft_rows_x<<<dim3(NROW, 2), 1024, 0, stream>>>(x, XTb);
  count_chunks<<<NCHUNK, 1024, 0, stream>>>(midx, K, chunk, cnt);
  colscan<<<16, 256, 0, stream>>>(cnt, tot);
  scan4096<<<1, 1024, 0, stream>>>(tot, off);
  scatter2<<<NCHUNK, 1024, 0, stream>>>(midx, cre, cim, K, chunk, cnt, off, bucket);
  spmm_col<<<2048, 256, 0, stream>>>(bucket, off, tot, XTb, Y);
  dft_rows_y<<<dim3(NROW, 2), 1024, 0, stream>>>(Y, out);      // writes out2
  gemm_mfma_partial<<<dim3(64, KC), 256, 0, stream>>>(xbf, W, part);
  reduce_bias<<<512, 256, 0, stream>>>(part, b, out);          // out += b + sum(part)
}